// Round 7
// baseline (3450.623 us; speedup 1.0000x reference)
//
#include <hip/hip_runtime.h>

// Bidirectional LSTM: V=32000, H=1024, S=512. fp32 in/out.
// Round-7 = Round-6 with the double-bias bug fixed (gx already contains
// bx+bh from the GEMM epilogue; stage C must NOT add them again).
//
//   K1: gx GEMM (proven round-0 kernel, ~215us): gx[512][8192] bf16,
//       gx = emb[tok].Wx + bx + bh.
//   K2: scan with INTRA-XCD exchange. 32 blocks per direction, selected as
//       blockIdx&7==0 (dir0) / ==1 (dir1): under the empirical round-robin
//       block->XCD mapping each direction lives on ONE XCD, so the h
//       exchange stays in that XCD's coherent L2 (~200cy RT vs ~1000+ at
//       MALL/agent scope -- the measured r4/r5 floor).
//       Correctness NEVER depends on placement: producers dual-publish
//       (plain store -> local L2, agent-scope store -> MALL); consumers
//       poll via sc0 (L2) loads and latch to agent-scope polling after 200
//       failed tries. Tags embedded in every word, verified after load.
//   Scan math: per block 32 units = 128 gate-rows; Wh slice as bf16 MFMA
//   A-fragments in 128 VGPRs; h split hi+lo bf16 (2 MFMAs) to keep
//   Wh(bf16) x h(~fp32) precision.

#define HID 1024
#define SEQ 512
#define NV  8192

typedef __attribute__((ext_vector_type(8))) __bf16 bf16x8;
typedef __attribute__((ext_vector_type(4))) float  f32x4;

__device__ __forceinline__ float bf2f(unsigned int u) {
  union { unsigned int i; float f; } v; v.i = u << 16; return v.f;
}
__device__ __forceinline__ unsigned int f2bf(float f) {
  union { float f; unsigned int i; } v; v.f = f;
  unsigned int u = v.i;
  return (u + 0x7fffu + ((u >> 16) & 1u)) >> 16;  // RNE
}
__device__ __forceinline__ unsigned int pk(float lo, float hi) {
  return f2bf(lo) | (f2bf(hi) << 16);
}
__device__ __forceinline__ float sigm(float x) { return 1.f / (1.f + __expf(-x)); }
__device__ __forceinline__ float ftanh(float x) {
  return 1.f - 2.f / (__expf(2.f * x) + 1.f);   // exact at saturation
}

// --- L2-path (sc0: bypass L1, hit the XCD-coherent L2) ---
__device__ __forceinline__ unsigned long long l2_load_u64(const unsigned long long* p) {
  unsigned long long r;
  asm volatile("global_load_dwordx2 %0, %1, off sc0\n\ts_waitcnt vmcnt(0)"
               : "=&v"(r) : "v"(p) : "memory");
  return r;
}
__device__ __forceinline__ void l2_load_pair(const unsigned long long* p,
                                             unsigned long long& a,
                                             unsigned long long& b) {
  asm volatile("global_load_dwordx2 %0, %2, off sc0\n\t"
               "global_load_dwordx2 %1, %2, off offset:8 sc0\n\t"
               "s_waitcnt vmcnt(0)"
               : "=&v"(a), "=&v"(b) : "v"(p) : "memory");
}
__device__ __forceinline__ void l2_store_u64(unsigned long long* p, unsigned long long v) {
  asm volatile("global_store_dwordx2 %0, %1, off" :: "v"(p), "v"(v) : "memory");
}

// ---------------------------------------------------------------------------
// K1: gx GEMM (round-0, proven): gx[s][n] = emb[tok[s]].Wx[n] + bx[n] + bh[n]
// ---------------------------------------------------------------------------
__global__ __launch_bounds__(256)
void gx_gemm(const int* __restrict__ tokens, const float* __restrict__ emb,
             const float* __restrict__ Wxf, const float* __restrict__ Wxb,
             const float* __restrict__ bxf, const float* __restrict__ bhf,
             const float* __restrict__ bxb, const float* __restrict__ bhb,
             unsigned short* __restrict__ gx)
{
  __shared__ alignas(16) unsigned short As[64][32];
  __shared__ alignas(16) unsigned short Bs[64][32];
  const int bm = blockIdx.x, bn = blockIdx.y;
  const int tid = threadIdx.x;
  const int wave = tid >> 6, lane = tid & 63;
  const int l16 = lane & 15, quad = lane >> 4;

  f32x4 acc0 = {0.f,0.f,0.f,0.f}, acc1 = {0.f,0.f,0.f,0.f};
  f32x4 acc2 = {0.f,0.f,0.f,0.f}, acc3 = {0.f,0.f,0.f,0.f};

  const int srow = tid >> 2, sch = tid & 3;
  const int tok = tokens[bm*64 + srow];
  const float* arow = emb + (size_t)tok * HID + sch*8;
  const int n = bn*64 + srow;
  const float* brow = ((n < 4096) ? (Wxf + (size_t)n*HID)
                                  : (Wxb + (size_t)(n-4096)*HID)) + sch*8;

  for (int k0 = 0; k0 < HID; k0 += 32) {
    const float4 a0 = *(const float4*)(arow + k0);
    const float4 a1 = *(const float4*)(arow + k0 + 4);
    const float4 b0 = *(const float4*)(brow + k0);
    const float4 b1 = *(const float4*)(brow + k0 + 4);
    uint4 ap, bp;
    ap.x = pk(a0.x, a0.y); ap.y = pk(a0.z, a0.w);
    ap.z = pk(a1.x, a1.y); ap.w = pk(a1.z, a1.w);
    bp.x = pk(b0.x, b0.y); bp.y = pk(b0.z, b0.w);
    bp.z = pk(b1.x, b1.y); bp.w = pk(b1.z, b1.w);
    *(uint4*)(&As[srow][sch*8]) = ap;
    *(uint4*)(&Bs[srow][sch*8]) = bp;
    __syncthreads();
    const bf16x8 af  = *(const bf16x8*)(&As[wave*16 + l16][quad*8]);
    const bf16x8 bf0 = *(const bf16x8*)(&Bs[ 0 + l16][quad*8]);
    const bf16x8 bf1 = *(const bf16x8*)(&Bs[16 + l16][quad*8]);
    const bf16x8 bf2 = *(const bf16x8*)(&Bs[32 + l16][quad*8]);
    const bf16x8 bf3 = *(const bf16x8*)(&Bs[48 + l16][quad*8]);
    acc0 = __builtin_amdgcn_mfma_f32_16x16x32_bf16(af, bf0, acc0, 0, 0, 0);
    acc1 = __builtin_amdgcn_mfma_f32_16x16x32_bf16(af, bf1, acc1, 0, 0, 0);
    acc2 = __builtin_amdgcn_mfma_f32_16x16x32_bf16(af, bf2, acc2, 0, 0, 0);
    acc3 = __builtin_amdgcn_mfma_f32_16x16x32_bf16(af, bf3, acc3, 0, 0, 0);
    __syncthreads();
  }

  const f32x4 accs[4] = {acc0, acc1, acc2, acc3};
  #pragma unroll
  for (int nt = 0; nt < 4; ++nt) {
    const int nn = bn*64 + nt*16 + l16;
    const int nl = nn & 4095;
    const float bias = ((nn < 4096) ? bxf[nl] : bxb[nl])
                     + ((nn < 4096) ? bhf[nl] : bhb[nl]);
    #pragma unroll
    for (int rg = 0; rg < 4; ++rg) {
      const int sq = bm*64 + wave*16 + quad*4 + rg;
      gx[(size_t)sq*NV + nn] = (unsigned short)f2bf(accs[nt][rg] + bias);
    }
  }
}

// ---------------------------------------------------------------------------
// K2: scan. 64 working blocks (blockIdx&7 < 2), 512 threads each.
// ---------------------------------------------------------------------------
__global__ __launch_bounds__(512, 1)
void bilstm_scan(const float* __restrict__ Whf, const float* __restrict__ Whb,
                 const unsigned short* __restrict__ gx,
                 unsigned long long* h_ex,    // [2 dir][2 par][1024] u64
                 float* __restrict__ out)     // [SEQ][2048] fp32
{
  const int role = blockIdx.x & 7;
  if (role >= 2) return;                    // 192 blocks exit, free their CUs
  const int d = role;                       // dir: XCD0 -> 0, XCD1 -> 1
  const int s = blockIdx.x >> 3;            // slot 0..31: units [s*32, s*32+32)
  const int tid  = threadIdx.x;
  const int wv   = tid >> 6;                // wave 0..7: rows [wv*16, wv*16+16)
  const int lane = tid & 63;
  const int grp  = lane >> 4;               // k-group 0..3 (A/B frag k-slice)

  __shared__ alignas(16) unsigned int hs_hi[2][512];  // h hi-bf16, packed x2
  __shared__ alignas(16) unsigned int hs_lo[2][512];  // h residual bf16

  const float* Wh = d ? Whb : Whf;

  // --- Wh slice -> 32 bf16 A-fragments (128 VGPRs) ---
  bf16x8 w[32];
  {
    const int rw = wv*16 + (lane & 15);
    const int ul = rw >> 2, gt = rw & 3;
    const float* wrow = Wh + ((size_t)(gt*HID + s*32 + ul))*HID + grp*8;
    #pragma unroll
    for (int ks = 0; ks < 32; ++ks) {
      const float4 q0 = *(const float4*)(wrow + ks*32);
      const float4 q1 = *(const float4*)(wrow + ks*32 + 4);
      uint4 pq;
      pq.x = pk(q0.x, q0.y); pq.y = pk(q0.z, q0.w);
      pq.z = pk(q1.x, q1.y); pq.w = pk(q1.z, q1.w);
      ((uint4*)w)[ks] = pq;
    }
  }

  // D-layout: col=lane&15 (batch, broadcast), row=grp*4+reg. Col-0 lanes
  // (lane&15==0) each own ONE unit with all 4 gates in acc[0..3].
  const bool isPub = ((lane & 15) == 0);
  const int u_glob = s*32 + wv*4 + grp;     // this pub lane's unit

  unsigned long long* hx = h_ex + (size_t)d * 2 * HID;   // [2][1024]

  // self-zero own words, both parities, both paths
  if (isPub) {
    l2_store_u64(hx + u_glob, 0ull);
    l2_store_u64(hx + HID + u_glob, 0ull);
    __hip_atomic_store(hx + u_glob, 0ull, __ATOMIC_RELAXED, __HIP_MEMORY_SCOPE_AGENT);
    __hip_atomic_store(hx + HID + u_glob, 0ull, __ATOMIC_RELAXED, __HIP_MEMORY_SCOPE_AGENT);
  }

  float c_state = 0.f;                      // on pub lanes
  bool agent_mode = false;                  // sticky fallback latch

  for (int t = 0; t < SEQ; ++t) {
    const int par  = t & 1;
    const int s_io = d ? (SEQ - 1 - t) : t;

    // gx prefetch (used ~1k cy later in stage C; nt keeps L2 clean).
    // gx ALREADY includes bx+bh -- do not add biases again (r6 bug).
    unsigned short gxr[4] = {0, 0, 0, 0};
    if (isPub) {
      const unsigned short* gp = gx + (size_t)s_io*NV + d*4096 + u_glob;
      #pragma unroll
      for (int g = 0; g < 4; ++g)
        gxr[g] = __builtin_nontemporal_load(gp + g*1024);
    }

    // --- stage A: h_{t-1} -> LDS (hi+lo bf16). 2 words/thread. ---
    if (t == 0) {
      hs_hi[0][tid] = 0u; hs_lo[0][tid] = 0u;
    } else {
      const unsigned long long* hp = hx + (par ^ 1) * HID;
      const unsigned long long* sp = hp + ((tid >> 4) << 5);  // own group sentinel
      const unsigned int need = (unsigned int)t;
      if (!agent_mode) {
        int tries = 0;
        for (;;) {
          const unsigned long long sv = l2_load_u64(sp);
          if ((unsigned int)(sv >> 32) == need) break;
          if (++tries > 200) { agent_mode = true; break; }
          __builtin_amdgcn_s_sleep(1);
        }
      }
      if (agent_mode) {
        while ((unsigned int)(__hip_atomic_load(sp, __ATOMIC_RELAXED,
                  __HIP_MEMORY_SCOPE_AGENT) >> 32) != need)
          __builtin_amdgcn_s_sleep(1);
      }
      const unsigned long long* dp = hp + tid * 2;
      unsigned long long u0, u1;
      if (!agent_mode) {
        l2_load_pair(dp, u0, u1);
      } else {
        u0 = __hip_atomic_load(dp,   __ATOMIC_RELAXED, __HIP_MEMORY_SCOPE_AGENT);
        u1 = __hip_atomic_load(dp+1, __ATOMIC_RELAXED, __HIP_MEMORY_SCOPE_AGENT);
      }
      int vtries = 0;
      while (((unsigned int)(u0 >> 32) != need) |
             ((unsigned int)(u1 >> 32) != need)) {
        __builtin_amdgcn_s_sleep(1);
        if (!agent_mode && ++vtries > 200) agent_mode = true;
        if (!agent_mode) {
          if ((unsigned int)(u0 >> 32) != need) u0 = l2_load_u64(dp);
          if ((unsigned int)(u1 >> 32) != need) u1 = l2_load_u64(dp+1);
        } else {
          if ((unsigned int)(u0 >> 32) != need)
            u0 = __hip_atomic_load(dp,   __ATOMIC_RELAXED, __HIP_MEMORY_SCOPE_AGENT);
          if ((unsigned int)(u1 >> 32) != need)
            u1 = __hip_atomic_load(dp+1, __ATOMIC_RELAXED, __HIP_MEMORY_SCOPE_AGENT);
        }
      }
      const float h0 = __uint_as_float((unsigned int)u0);
      const float h1 = __uint_as_float((unsigned int)u1);
      const unsigned int b0 = f2bf(h0), b1 = f2bf(h1);
      hs_hi[par][tid] = b0 | (b1 << 16);
      hs_lo[par][tid] = f2bf(h0 - bf2f(b0)) | (f2bf(h1 - bf2f(b1)) << 16);
    }
    __syncthreads();                        // single barrier per step

    // --- stage B: 64 MFMA (hi+lo), 4 independent chains ---
    const char* phi = (const char*)&hs_hi[par][0] + grp*16;
    const char* plo = (const char*)&hs_lo[par][0] + grp*16;
    f32x4 a0 = {0.f,0.f,0.f,0.f}, a1 = {0.f,0.f,0.f,0.f};
    f32x4 a2 = {0.f,0.f,0.f,0.f}, a3 = {0.f,0.f,0.f,0.f};
    #pragma unroll
    for (int ks = 0; ks < 32; ks += 2) {
      a0 = __builtin_amdgcn_mfma_f32_16x16x32_bf16(w[ks],
             *(const bf16x8*)(phi + ks*64), a0, 0, 0, 0);
      a1 = __builtin_amdgcn_mfma_f32_16x16x32_bf16(w[ks],
             *(const bf16x8*)(plo + ks*64), a1, 0, 0, 0);
      a2 = __builtin_amdgcn_mfma_f32_16x16x32_bf16(w[ks+1],
             *(const bf16x8*)(phi + (ks+1)*64), a2, 0, 0, 0);
      a3 = __builtin_amdgcn_mfma_f32_16x16x32_bf16(w[ks+1],
             *(const bf16x8*)(plo + (ks+1)*64), a3, 0, 0, 0);
    }
    const f32x4 acc = (a0 + a1) + (a2 + a3);

    // --- stage C: gates on pub lanes (unit-per-lane, gate-per-reg) ---
    if (isPub) {
      const float G0 = acc[0] + bf2f(gxr[0]);
      const float G1 = acc[1] + bf2f(gxr[1]);
      const float G2 = acc[2] + bf2f(gxr[2]);
      const float G3 = acc[3] + bf2f(gxr[3]);
      const float gi = sigm(G0), gf = sigm(G1), go = sigm(G2), gg = ftanh(G3);
      c_state = gf * c_state + gi * gg;
      const float hv = go * ftanh(c_state);
      if (t + 1 < SEQ) {
        const unsigned long long pkd =
            ((unsigned long long)(unsigned int)(t + 1) << 32)
          | (unsigned long long)__float_as_uint(hv);
        unsigned long long* wp = hx + par*HID + u_glob;
        l2_store_u64(wp, pkd);                               // L2 fast path
        __hip_atomic_store(wp, pkd, __ATOMIC_RELAXED,        // MALL path
                           __HIP_MEMORY_SCOPE_AGENT);
      }
      __builtin_nontemporal_store(hv, out + (size_t)s_io*2048 + d*HID + u_glob);
    }
    // no end barrier: next stage-A writes hs[par^1], read-disjoint from
    // this step's hs[par] readers; exchange reuse safe by tag monotonicity.
  }
}

// ---------------------------------------------------------------------------
extern "C" void kernel_launch(void* const* d_in, const int* in_sizes, int n_in,
                              void* d_out, int out_size, void* d_ws, size_t ws_size,
                              hipStream_t stream) {
  const int*   tokens = (const int*)d_in[0];
  const float* emb = (const float*)d_in[3];
  const float* Wxf = (const float*)d_in[4];
  const float* Whf = (const float*)d_in[5];
  const float* bxf = (const float*)d_in[6];
  const float* bhf = (const float*)d_in[7];
  const float* Wxb = (const float*)d_in[8];
  const float* Whb = (const float*)d_in[9];
  const float* bxb = (const float*)d_in[10];
  const float* bhb = (const float*)d_in[11];

  char* ws = (char*)d_ws;
  unsigned short* gx = (unsigned short*)ws;                            // 8 MB
  unsigned long long* h_ex = (unsigned long long*)(ws + (size_t)8*1024*1024); // 32 KB

  gx_gemm<<<dim3(8,128), dim3(256), 0, stream>>>(tokens, emb, Wxf, Wxb,
                                                 bxf, bhf, bxb, bhb, gx);

  bilstm_scan<<<dim3(256), dim3(512), 0, stream>>>(Whf, Whb,
                                                   gx, h_ex, (float*)d_out);
}